// Round 12
// baseline (155.978 us; speedup 1.0000x reference)
//
#include <hip/hip_runtime.h>
#include <stdint.h>

// CSWin attention, MI355X/gfx950 — r21: r20 pipeline, correct VGPR budget.
// Shapes: B=2, H=W=64, N=4, DIM=128, HEADS=4, HEAD_DIM=32, SPLIT=2.
// Grid 256 = (window,head), 1 block/CU; block 1024 (16 waves);
// wave = 32 q-rows (2 m-tiles). LDS 64KB: VT 32K + KS 32K.
//
// r21: r20's pipeline was correct (passed) but launch_bounds(1024,2) caps
// VGPR at 512-per-SIMD / 8 waves = 64 -> spill (WRITE 231MB, VGPR=64).
// Resolved cap model (all rounds consistent): cap = 512 / (arg x B/256).
// (1024,1) -> cap 128; demand ~120 (r19's ~88 + bv early-live 16 + ak
// dbuf 16). LDS 64KB already limits to 1 block/CU, so arg=1 loses nothing.
// Schedule (from r20):
//  * bv reads hoisted to iteration top: wait hides under QK MFMAs + softmax.
//  * ak double-buffered 1 iter ahead (named regs, 2x-unrolled loop):
//    QK's lgkmcnt drains reads issued a full body earlier.
//  * s_setprio(1) around MFMA clusters (free-running waves, T5 regime).
// Predicted: VGPR 104-128, WRITE ~16.4MB, FETCH ~25MB, conflicts ~1.1M,
// kernel ~33-38us (JSON total ~102-107 vs r19's 112.9). If VGPR=128 AND
// WRITE balloons -> demand overflow, drop ak dbuf next. If clean and JSON
// ~113 -> exposed-latency theory dead -> declare structural floor.

typedef __bf16 bf16x8 __attribute__((ext_vector_type(8)));
typedef float f32x4 __attribute__((ext_vector_type(4)));
typedef float f32x2 __attribute__((ext_vector_type(2)));

#if __has_builtin(__builtin_amdgcn_exp2f)
#define EXP2F __builtin_amdgcn_exp2f
#else
#define EXP2F exp2f
#endif

union U4 { uint4 u; bf16x8 v; unsigned short s[8]; };

__device__ __forceinline__ float bf2f(unsigned short h){ union{unsigned u;float f;}x; x.u=((unsigned)h)<<16; return x.f; }

// f32 pair -> packed bf16 dword (lo in low half), RTNE. 1 instr.
__device__ __forceinline__ unsigned cvtpk(float lo, float hi){
  unsigned d;
  asm("v_cvt_pk_bf16_f32 %0, %1, %2" : "=v"(d) : "v"(lo), "v"(hi));
  return d;
}
__device__ __forceinline__ U4 pack8(float4 a, float4 b){
  U4 r;
  r.u.x = cvtpk(a.x, a.y); r.u.y = cvtpk(a.z, a.w);
  r.u.z = cvtpk(b.x, b.y); r.u.w = cvtpk(b.z, b.w);
  return r;
}

// permlane swap pair primitives (gfx950).
__device__ __forceinline__ void pls32(unsigned &a, unsigned &b){
#if __has_builtin(__builtin_amdgcn_permlane32_swap)
  auto r = __builtin_amdgcn_permlane32_swap(a, b, false, false);
  a = r[0]; b = r[1];
#else
  unsigned sa_ = __shfl_xor(a, 32), sb_ = __shfl_xor(b, 32);
  bool hi = ((threadIdx.x & 32) != 0);
  unsigned na = hi ? sb_ : a, nb = hi ? b : sa_;
  a = na; b = nb;
#endif
}
__device__ __forceinline__ void pls16(unsigned &a, unsigned &b){
#if __has_builtin(__builtin_amdgcn_permlane16_swap)
  auto r = __builtin_amdgcn_permlane16_swap(a, b, false, false);
  a = r[0]; b = r[1];
#else
  unsigned sa_ = __shfl_xor(a, 16), sb_ = __shfl_xor(b, 16);
  bool hi = ((threadIdx.x & 16) != 0);
  unsigned na = hi ? sb_ : a, nb = hi ? b : sa_;
  a = na; b = nb;
#endif
}

// In-register P transpose. Input: w[t][i] = packed P[q=n][k=16t+4*qd+{2i,2i+1}]
// Output A-frags: ap0 = P[row=n][k=qd*8..+7], ap1 = same for k+32.
__device__ __forceinline__ void xpose_p(const unsigned w[4][2], U4& ap0, U4& ap1)
{
  unsigned a0 = w[0][0], b0 = w[1][0]; pls32(a0, b0); pls16(a0, b0);
  unsigned a1 = w[0][1], b1 = w[1][1]; pls32(a1, b1); pls16(a1, b1);
  ap0.u.x = a0; ap0.u.y = a1; ap0.u.z = b0; ap0.u.w = b1;
  unsigned c0 = w[2][0], d0 = w[3][0]; pls32(c0, d0); pls16(c0, d0);
  unsigned c1 = w[2][1], d1 = w[3][1]; pls32(c1, d1); pls16(c1, d1);
  ap1.u.x = c0; ap1.u.y = c1; ap1.u.z = d0; ap1.u.w = d1;
}

#define C_SCALE 0.25506953149031837f  // (1/sqrt(32)) * log2(e)
#define M_SHIFT 20.0f                 // fixed log2-domain softmax shift

// LDS: VT bf16 [32 ch][512 tok], 1KB/row, byte = R*1024 + ((T*2)^((R&7)<<4))
//      KS bf16 [512 tok][32 ch], 64B/row, byte = T*64 + (off ^ (((T>>1)&3)<<4))
#define VT_OFF 0
#define KS_OFF 32768
#define LDS_BYTES 65536

// One chunk body: uses C0..C3 (K frags loaded >=1 body ago), prefetches
// N0..N3 for chunk CK_+1. bv issued at top so its wait hides under softmax.
#define CHUNK(CK_, C0,C1,C2,C3, N0,N1,N2,N3)                                   \
  {                                                                            \
    const int ck_ = (CK_);                                                     \
    /* current-iter V fragments: land during QK+softmax */                     \
    const unsigned char* vr0 = smem + VT_OFF + n * 1024 + ck_ * 128;           \
    const unsigned char* vr1 = vr0 + 16 * 1024;                                \
    U4 bv00, bv01, bv10, bv11;                                                 \
    bv00.u = *(const uint4*)(vr0 + xb0);                                       \
    bv01.u = *(const uint4*)(vr0 + xb1);                                       \
    bv10.u = *(const uint4*)(vr1 + xb0);                                       \
    bv11.u = *(const uint4*)(vr1 + xb1);                                       \
    /* next-iter K fragments (1-deep LDS prefetch) */                          \
    if (ck_ < 7){                                                              \
      const unsigned char* kb_ = kbase + (ck_ + 1) * 4096;                     \
      N0.u = *(const uint4*)(kb_);                                             \
      N1.u = *(const uint4*)(kb_ + 1024);                                      \
      N2.u = *(const uint4*)(kb_ + 2048);                                      \
      N3.u = *(const uint4*)(kb_ + 3072);                                      \
    }                                                                          \
    const f32x4 zero = {0.f,0.f,0.f,0.f};                                      \
    f32x4 sa[4], sb[4];                                                        \
    __builtin_amdgcn_s_setprio(1);                                             \
    sa[0] = __builtin_amdgcn_mfma_f32_16x16x32_bf16(C0.v, bqa.v, zero, 0, 0, 0); \
    sb[0] = __builtin_amdgcn_mfma_f32_16x16x32_bf16(C0.v, bqb.v, zero, 0, 0, 0); \
    sa[1] = __builtin_amdgcn_mfma_f32_16x16x32_bf16(C1.v, bqa.v, zero, 0, 0, 0); \
    sb[1] = __builtin_amdgcn_mfma_f32_16x16x32_bf16(C1.v, bqb.v, zero, 0, 0, 0); \
    sa[2] = __builtin_amdgcn_mfma_f32_16x16x32_bf16(C2.v, bqa.v, zero, 0, 0, 0); \
    sb[2] = __builtin_amdgcn_mfma_f32_16x16x32_bf16(C2.v, bqb.v, zero, 0, 0, 0); \
    sa[3] = __builtin_amdgcn_mfma_f32_16x16x32_bf16(C3.v, bqa.v, zero, 0, 0, 0); \
    sb[3] = __builtin_amdgcn_mfma_f32_16x16x32_bf16(C3.v, bqb.v, zero, 0, 0, 0); \
    __builtin_amdgcn_s_setprio(0);                                             \
    if (ck_ == cka){                                                           \
      bool dq = (qd == (n >> 2));                                              \
      _Pragma("unroll")                                                        \
      for (int r = 0; r < 4; r++)                                              \
        if (dq && r != (n & 3)){ sa[ta][r] = -1e30f; sb[ta+1][r] = -1e30f; }   \
    }                                                                          \
    unsigned wA[4][2], wB[4][2];                                               \
    {                                                                          \
      const f32x2 m2 = {-M_SHIFT, -M_SHIFT};                                   \
      _Pragma("unroll")                                                        \
      for (int t = 0; t < 4; t++){                                             \
        f32x2 y0 = (f32x2){sa[t][0], sa[t][1]} * C_SCALE + m2;                 \
        f32x2 y1 = (f32x2){sa[t][2], sa[t][3]} * C_SCALE + m2;                 \
        float p0 = EXP2F(y0.x), p1 = EXP2F(y0.y);                              \
        float p2 = EXP2F(y1.x), p3 = EXP2F(y1.y);                              \
        la2 += (f32x2){p0, p1}; la2 += (f32x2){p2, p3};                        \
        wA[t][0] = cvtpk(p0, p1); wA[t][1] = cvtpk(p2, p3);                    \
      }                                                                        \
      _Pragma("unroll")                                                        \
      for (int t = 0; t < 4; t++){                                             \
        f32x2 y0 = (f32x2){sb[t][0], sb[t][1]} * C_SCALE + m2;                 \
        f32x2 y1 = (f32x2){sb[t][2], sb[t][3]} * C_SCALE + m2;                 \
        float p0 = EXP2F(y0.x), p1 = EXP2F(y0.y);                              \
        float p2 = EXP2F(y1.x), p3 = EXP2F(y1.y);                              \
        lb2 += (f32x2){p0, p1}; lb2 += (f32x2){p2, p3};                        \
        wB[t][0] = cvtpk(p0, p1); wB[t][1] = cvtpk(p2, p3);                    \
      }                                                                        \
    }                                                                          \
    U4 apA0, apA1, apB0, apB1;                                                 \
    xpose_p(wA, apA0, apA1);                                                   \
    xpose_p(wB, apB0, apB1);                                                   \
    __builtin_amdgcn_s_setprio(1);                                             \
    o0a = __builtin_amdgcn_mfma_f32_16x16x32_bf16(apA0.v, bv00.v, o0a, 0, 0, 0); \
    o0a = __builtin_amdgcn_mfma_f32_16x16x32_bf16(apA1.v, bv01.v, o0a, 0, 0, 0); \
    o1a = __builtin_amdgcn_mfma_f32_16x16x32_bf16(apA0.v, bv10.v, o1a, 0, 0, 0); \
    o1a = __builtin_amdgcn_mfma_f32_16x16x32_bf16(apA1.v, bv11.v, o1a, 0, 0, 0); \
    o0b = __builtin_amdgcn_mfma_f32_16x16x32_bf16(apB0.v, bv00.v, o0b, 0, 0, 0); \
    o0b = __builtin_amdgcn_mfma_f32_16x16x32_bf16(apB1.v, bv01.v, o0b, 0, 0, 0); \
    o1b = __builtin_amdgcn_mfma_f32_16x16x32_bf16(apB0.v, bv10.v, o1b, 0, 0, 0); \
    o1b = __builtin_amdgcn_mfma_f32_16x16x32_bf16(apB1.v, bv11.v, o1b, 0, 0, 0); \
    __builtin_amdgcn_s_setprio(0);                                             \
  }

__global__ __launch_bounds__(1024, 1) void cswin_attn_kernel(
    const float* __restrict__ qg,
    const float* __restrict__ kg,
    const float* __restrict__ vg,
    const float* __restrict__ cwg,
    float* __restrict__ outg)
{
  __shared__ __align__(16) unsigned char smem[LDS_BYTES];
  const int tid = threadIdx.x;
  const int lane = tid & 63;
  const int wave = tid >> 6;          // 0..15
  const int qd = lane >> 4;
  const int n  = lane & 15;

  const int swn = (n & 7) << 2;            // VT read swizzle (dword units)
  const int xb0 = ((4 * qd) ^ swn) << 2;   // VT: byte off of swizzled dword 4qd
  const int xb1 = xb0 ^ 64;

  const int bh = blockIdx.x;               // (window,head) 0..255
  const int head = bh & 3;
  const int bw = bh >> 2;
  const int b  = bw >> 5;
  const int jj = bw & 31;

  // token l: offset = wbase + (l>>3)*32768 + ((l>>2)&1)*512 + (l&3)*128
  const size_t wbase = (size_t)b * 2097152 + (size_t)(jj * 2) * 512 + head * 32;
  const size_t lane_base = wbase + (size_t)(n >> 3) * 32768 + (size_t)((n >> 2) & 1) * 512 +
                           (size_t)(n & 3) * 128 + qd * 8;

  const int row0  = wave * 32;          // this wave's 2 m-tiles
  const int tilea = row0 >> 4;          // even; m-tile B = tilea+1
  const int cka   = tilea >> 2;         // chunk holding both diag tiles
  const int ta    = tilea & 3;          // in-chunk tile idx of A's diag

  // ---- issue Q loads first (latency hidden under staging) ----
  float4 qra0, qra1, qrb0, qrb1;
  {
    const float* qa = qg + lane_base + (size_t)tilea * 65536;
    const float* qb = qa + 65536;
    qra0 = ((const float4*)qa)[0]; qra1 = ((const float4*)qa)[1];
    qrb0 = ((const float4*)qb)[0]; qrb1 = ((const float4*)qb)[1];
  }

  // ---- stage V -> VT and K -> KS, once per win-head, coalesced ----
  // slice (T, p): T = rr*128 + tid>>3, p = tid&7 (8 lanes = one token's 128B).
  {
    const int tk = tid >> 3;
    const int p  = tid & 7;
    float4 va0, va1, va2, va3, ka0, ka1, ka2, ka3;
    {
      size_t o0 = wbase + (size_t)((tk) >> 3) * 32768 + (size_t)(((tk) >> 2) & 1) * 512 + (size_t)((tk) & 3) * 128 + p * 4;
      size_t o1 = wbase + (size_t)((128 + tk) >> 3) * 32768 + (size_t)(((128 + tk) >> 2) & 1) * 512 + (size_t)((128 + tk) & 3) * 128 + p * 4;
      size_t o2 = wbase + (size_t)((256 + tk) >> 3) * 32768 + (size_t)(((256 + tk) >> 2) & 1) * 512 + (size_t)((256 + tk) & 3) * 128 + p * 4;
      size_t o3 = wbase + (size_t)((384 + tk) >> 3) * 32768 + (size_t)(((384 + tk) >> 2) & 1) * 512 + (size_t)((384 + tk) & 3) * 128 + p * 4;
      va0 = *(const float4*)(vg + o0); ka0 = *(const float4*)(kg + o0);
      va1 = *(const float4*)(vg + o1); ka1 = *(const float4*)(kg + o1);
      va2 = *(const float4*)(vg + o2); ka2 = *(const float4*)(kg + o2);
      va3 = *(const float4*)(vg + o3); ka3 = *(const float4*)(kg + o3);
    }
    const int R0 = 4 * p;
#define STAGE_WR(VA, KA, TT)                                                         \
    {                                                                                \
      const int T_ = (TT);                                                           \
      unsigned short h0 = (unsigned short)cvtpk((VA).x, (VA).x);                     \
      unsigned short h1 = (unsigned short)cvtpk((VA).y, (VA).y);                     \
      unsigned short h2 = (unsigned short)cvtpk((VA).z, (VA).z);                     \
      unsigned short h3 = (unsigned short)cvtpk((VA).w, (VA).w);                     \
      *(unsigned short*)(smem + VT_OFF + (R0+0) * 1024 + ((T_*2) ^ (((R0+0)&7)<<4))) = h0; \
      *(unsigned short*)(smem + VT_OFF + (R0+1) * 1024 + ((T_*2) ^ (((R0+1)&7)<<4))) = h1; \
      *(unsigned short*)(smem + VT_OFF + (R0+2) * 1024 + ((T_*2) ^ (((R0+2)&7)<<4))) = h2; \
      *(unsigned short*)(smem + VT_OFF + (R0+3) * 1024 + ((T_*2) ^ (((R0+3)&7)<<4))) = h3; \
      uint2 kw; kw.x = cvtpk((KA).x, (KA).y); kw.y = cvtpk((KA).z, (KA).w);          \
      *(uint2*)(smem + KS_OFF + T_ * 64 + ((p*8) ^ (((T_>>1)&3)<<4))) = kw;          \
    }
    STAGE_WR(va0, ka0, tk)
    STAGE_WR(va1, ka1, 128 + tk)
    STAGE_WR(va2, ka2, 256 + tk)
    STAGE_WR(va3, ka3, 384 + tk)
#undef STAGE_WR
  }

  // Q pack overlaps the staging drain (before the barrier)
  U4 bqa = pack8(qra0, qra1);
  U4 bqb = pack8(qrb0, qrb1);

  __syncthreads();

  f32x4 o0a={0,0,0,0}, o1a={0,0,0,0}, o0b={0,0,0,0}, o1b={0,0,0,0};
  f32x2 la2 = {0.f,0.f}, lb2 = {0.f,0.f};   // packed per-lane softmax sums

  // per-lane KS read base: token n of each tile, ch qd*8..+7 (swizzled).
  // swizzle key for row T=16t+n is ((T>>1)&3) = ((n>>1)&3)  (16t ≡ 0 mod 8).
  const int kxb = (qd * 16) ^ (((n >> 1) & 3) << 4);
  const unsigned char* kbase = smem + KS_OFF + n * 64 + kxb;

  // ---- prologue: K fragments for chunk 0 ----
  U4 aka0, aka1, aka2, aka3, akb0, akb1, akb2, akb3;
  aka0.u = *(const uint4*)(kbase);
  aka1.u = *(const uint4*)(kbase + 1024);
  aka2.u = *(const uint4*)(kbase + 2048);
  aka3.u = *(const uint4*)(kbase + 3072);

#pragma unroll 1
  for (int cc = 0; cc < 4; cc++){
    CHUNK(cc * 2,     aka0, aka1, aka2, aka3, akb0, akb1, akb2, akb3)
    CHUNK(cc * 2 + 1, akb0, akb1, akb2, akb3, aka0, aka1, aka2, aka3)
  }

  // ---- conv weights (global loads overlap the reductions below) ----
  float w9[2][9];
#pragma unroll
  for (int nt = 0; nt < 2; nt++){
    int c = head * 32 + nt * 16 + n;
#pragma unroll
    for (int t9 = 0; t9 < 9; t9++) w9[nt][t9] = cwg[c * 9 + t9];
  }

  // ---- final cross-lane l reduction (once, not per chunk) ----
  float la = la2.x + la2.y, lb = lb2.x + lb2.y;
  la += __shfl_xor(la, 16); la += __shfl_xor(la, 32);
  lb += __shfl_xor(lb, 16); lb += __shfl_xor(lb, 32);

  const float ila = 1.f / la, ilb = 1.f / lb;

  // ---- epilogue: compute both nt halves first, then store adjacently ----
#pragma unroll
  for (int mt = 0; mt < 2; mt++){
    const int m0 = row0 + mt * 16;
    const float ilv = mt ? ilb : ila;
    const f32x4 oo0 = mt ? o0b : o0a;
    const f32x4 oo1 = mt ? o1b : o1a;
    float il[4];
#pragma unroll
    for (int r = 0; r < 4; r++) il[r] = __shfl(ilv, qd * 4 + r);

    const int sp = (m0 >> 2) + qd;
    const int h_ = sp >> 1, w_ = sp & 1;

    float accs[2], cw2[2], vfs[2][4];
#pragma unroll
    for (int nt = 0; nt < 2; nt++){
      const int d = nt * 16 + n;
      const unsigned char* VTd = smem + VT_OFF + d * 1024;   // (d&7)==(n&7)
      float acc = 0.f;
#pragma unroll
      for (int dy = -1; dy <= 1; dy++){
        int h2 = h_ + dy;
        bool hv = (h2 >= 0) && (h2 <= 63);
        int h2c = hv ? h2 : h_;   // safe in-range address for masked lanes
#pragma unroll
        for (int wp = 0; wp < 2; wp++){
          bool valid = hv && !((dy == 0) && (wp == w_));
          int ti = (dy + 1) * 3 + 1 + wp - w_;
          int spn = h2c * 2 + wp;
          uint2 sv = *(const uint2*)(VTd + (((2 * spn) ^ swn) << 2));
          float s = bf2f((unsigned short)(sv.x & 0xffff)) + bf2f((unsigned short)(sv.x >> 16))
                  + bf2f((unsigned short)(sv.y & 0xffff)) + bf2f((unsigned short)(sv.y >> 16));
          acc += (valid ? w9[nt][ti] : 0.f) * s;
        }
      }
      accs[nt] = acc;
      cw2[nt] = w9[nt][4];
      uint2 vv4 = *(const uint2*)(VTd + ((((m0 >> 1) + 2 * qd) ^ swn) << 2));
      vfs[nt][0] = bf2f((unsigned short)(vv4.x & 0xffff));
      vfs[nt][1] = bf2f((unsigned short)(vv4.x >> 16));
      vfs[nt][2] = bf2f((unsigned short)(vv4.y & 0xffff));
      vfs[nt][3] = bf2f((unsigned short)(vv4.y >> 16));
    }

    const size_t obase = (size_t)b * 2097152 + (size_t)h_ * 32768 +
                         (size_t)(jj * 2 + w_) * 512 + head * 32;
#pragma unroll
    for (int r = 0; r < 4; r++){
      float r0 = oo0[r] * il[r] + accs[0] + cw2[0] * vfs[0][r];
      float r1 = oo1[r] * il[r] + accs[1] + cw2[1] * vfs[1][r];
      outg[obase + (size_t)r * 128 + n]      = r0;   // line half 1
      outg[obase + (size_t)r * 128 + 16 + n] = r1;   // line half 2 (adjacent)
    }
  }
}

extern "C" void kernel_launch(void* const* d_in, const int* in_sizes, int n_in,
                              void* d_out, int out_size, void* d_ws, size_t ws_size,
                              hipStream_t stream) {
  (void)in_sizes; (void)n_in; (void)d_ws; (void)ws_size; (void)out_size;
  cswin_attn_kernel<<<dim3(256), dim3(1024), 0, stream>>>(
      (const float*)d_in[0], (const float*)d_in[1], (const float*)d_in[2],
      (const float*)d_in[3], (float*)d_out);
}

// Round 13
// 119.366 us; speedup vs baseline: 1.3067x; 1.3067x over previous
//
#include <hip/hip_runtime.h>
#include <stdint.h>

// CSWin attention, MI355X/gfx950 — r22: r20 pipeline at a register-sane shape.
// Shapes: B=2, H=W=64, N=4, DIM=128, HEADS=4, HEAD_DIM=32, SPLIT=2.
// Grid 512 = (window,head) x 2 row-halves; block 512 (8 waves);
// wave = 32 q-rows (2 m-tiles, r17 hot loop). LDS 64KB: VT 32K + KS 32K.
// 2 blocks/CU (128KB LDS) -> 16 waves/CU = 4/SIMD.
//
// r22: B=1024 blocks are VGPR-pinned to 64 by hipcc regardless of
// launch_bounds arg (r20 arg=2 and r21 arg=1 both alloc 64 + 231MB spill).
// Validated cap model for B<=512: cap = 512/(blockWavesPerEU x arg):
// (256,3)->72<=170, (256,2)->88-104<=256, (512,2)->52(demand)<=128,
// (512,8)->32. So: B=512, arg=2 -> cap 128, demand ~110 fits.
//  * grid 512: 2 blocks per win-head (halves share bid&255 -> same XCD slot,
//    2nd K/V read is L2-hit). Staging redundancy 2x (vs r19 1x, r17 4x).
//  * hot loop = r20/r21's verified pipeline: bv reads hoisted to iter top
//    (wait hides under QK+softmax), ak double-buffered 1 iter ahead
//    (lgkm drains reads issued a full body earlier), setprio around MFMAs.
//  * bonus: the 2 co-resident blocks' staging/compute phases overlap.
// Predicted: VGPR 96-128 (64 -> pinning is B-independent, abandon pipeline),
// WRITE ~16.4MB, FETCH ~25-33MB, conflicts ~1.1M, kernel ~30-36us
// (JSON ~100-107). Clean but JSON ~113 -> latency theory dead -> floor.

typedef __bf16 bf16x8 __attribute__((ext_vector_type(8)));
typedef float f32x4 __attribute__((ext_vector_type(4)));
typedef float f32x2 __attribute__((ext_vector_type(2)));

#if __has_builtin(__builtin_amdgcn_exp2f)
#define EXP2F __builtin_amdgcn_exp2f
#else
#define EXP2F exp2f
#endif

union U4 { uint4 u; bf16x8 v; unsigned short s[8]; };

__device__ __forceinline__ float bf2f(unsigned short h){ union{unsigned u;float f;}x; x.u=((unsigned)h)<<16; return x.f; }

// f32 pair -> packed bf16 dword (lo in low half), RTNE. 1 instr.
__device__ __forceinline__ unsigned cvtpk(float lo, float hi){
  unsigned d;
  asm("v_cvt_pk_bf16_f32 %0, %1, %2" : "=v"(d) : "v"(lo), "v"(hi));
  return d;
}
__device__ __forceinline__ U4 pack8(float4 a, float4 b){
  U4 r;
  r.u.x = cvtpk(a.x, a.y); r.u.y = cvtpk(a.z, a.w);
  r.u.z = cvtpk(b.x, b.y); r.u.w = cvtpk(b.z, b.w);
  return r;
}

// permlane swap pair primitives (gfx950).
__device__ __forceinline__ void pls32(unsigned &a, unsigned &b){
#if __has_builtin(__builtin_amdgcn_permlane32_swap)
  auto r = __builtin_amdgcn_permlane32_swap(a, b, false, false);
  a = r[0]; b = r[1];
#else
  unsigned sa_ = __shfl_xor(a, 32), sb_ = __shfl_xor(b, 32);
  bool hi = ((threadIdx.x & 32) != 0);
  unsigned na = hi ? sb_ : a, nb = hi ? b : sa_;
  a = na; b = nb;
#endif
}
__device__ __forceinline__ void pls16(unsigned &a, unsigned &b){
#if __has_builtin(__builtin_amdgcn_permlane16_swap)
  auto r = __builtin_amdgcn_permlane16_swap(a, b, false, false);
  a = r[0]; b = r[1];
#else
  unsigned sa_ = __shfl_xor(a, 16), sb_ = __shfl_xor(b, 16);
  bool hi = ((threadIdx.x & 16) != 0);
  unsigned na = hi ? sb_ : a, nb = hi ? b : sa_;
  a = na; b = nb;
#endif
}

// In-register P transpose. Input: w[t][i] = packed P[q=n][k=16t+4*qd+{2i,2i+1}]
// Output A-frags: ap0 = P[row=n][k=qd*8..+7], ap1 = same for k+32.
__device__ __forceinline__ void xpose_p(const unsigned w[4][2], U4& ap0, U4& ap1)
{
  unsigned a0 = w[0][0], b0 = w[1][0]; pls32(a0, b0); pls16(a0, b0);
  unsigned a1 = w[0][1], b1 = w[1][1]; pls32(a1, b1); pls16(a1, b1);
  ap0.u.x = a0; ap0.u.y = a1; ap0.u.z = b0; ap0.u.w = b1;
  unsigned c0 = w[2][0], d0 = w[3][0]; pls32(c0, d0); pls16(c0, d0);
  unsigned c1 = w[2][1], d1 = w[3][1]; pls32(c1, d1); pls16(c1, d1);
  ap1.u.x = c0; ap1.u.y = c1; ap1.u.z = d0; ap1.u.w = d1;
}

#define C_SCALE 0.25506953149031837f  // (1/sqrt(32)) * log2(e)
#define M_SHIFT 20.0f                 // fixed log2-domain softmax shift

// LDS: VT bf16 [32 ch][512 tok], 1KB/row, byte = R*1024 + ((T*2)^((R&7)<<4))
//      KS bf16 [512 tok][32 ch], 64B/row, byte = T*64 + (off ^ (((T>>1)&3)<<4))
#define VT_OFF 0
#define KS_OFF 32768
#define LDS_BYTES 65536

// One chunk body: uses C0..C3 (K frags loaded >=1 body ago), prefetches
// N0..N3 for chunk CK_+1. bv issued at top so its wait hides under softmax.
#define CHUNK(CK_, C0,C1,C2,C3, N0,N1,N2,N3)                                   \
  {                                                                            \
    const int ck_ = (CK_);                                                     \
    /* current-iter V fragments: land during QK+softmax */                     \
    const unsigned char* vr0 = smem + VT_OFF + n * 1024 + ck_ * 128;           \
    const unsigned char* vr1 = vr0 + 16 * 1024;                                \
    U4 bv00, bv01, bv10, bv11;                                                 \
    bv00.u = *(const uint4*)(vr0 + xb0);                                       \
    bv01.u = *(const uint4*)(vr0 + xb1);                                       \
    bv10.u = *(const uint4*)(vr1 + xb0);                                       \
    bv11.u = *(const uint4*)(vr1 + xb1);                                       \
    /* next-iter K fragments (1-deep LDS prefetch) */                          \
    if (ck_ < 7){                                                              \
      const unsigned char* kb_ = kbase + (ck_ + 1) * 4096;                     \
      N0.u = *(const uint4*)(kb_);                                             \
      N1.u = *(const uint4*)(kb_ + 1024);                                      \
      N2.u = *(const uint4*)(kb_ + 2048);                                      \
      N3.u = *(const uint4*)(kb_ + 3072);                                      \
    }                                                                          \
    const f32x4 zero = {0.f,0.f,0.f,0.f};                                      \
    f32x4 sa[4], sb[4];                                                        \
    __builtin_amdgcn_s_setprio(1);                                             \
    sa[0] = __builtin_amdgcn_mfma_f32_16x16x32_bf16(C0.v, bqa.v, zero, 0, 0, 0); \
    sb[0] = __builtin_amdgcn_mfma_f32_16x16x32_bf16(C0.v, bqb.v, zero, 0, 0, 0); \
    sa[1] = __builtin_amdgcn_mfma_f32_16x16x32_bf16(C1.v, bqa.v, zero, 0, 0, 0); \
    sb[1] = __builtin_amdgcn_mfma_f32_16x16x32_bf16(C1.v, bqb.v, zero, 0, 0, 0); \
    sa[2] = __builtin_amdgcn_mfma_f32_16x16x32_bf16(C2.v, bqa.v, zero, 0, 0, 0); \
    sb[2] = __builtin_amdgcn_mfma_f32_16x16x32_bf16(C2.v, bqb.v, zero, 0, 0, 0); \
    sa[3] = __builtin_amdgcn_mfma_f32_16x16x32_bf16(C3.v, bqa.v, zero, 0, 0, 0); \
    sb[3] = __builtin_amdgcn_mfma_f32_16x16x32_bf16(C3.v, bqb.v, zero, 0, 0, 0); \
    __builtin_amdgcn_s_setprio(0);                                             \
    if (ck_ == cka){                                                           \
      bool dq = (qd == (n >> 2));                                              \
      _Pragma("unroll")                                                        \
      for (int r = 0; r < 4; r++)                                              \
        if (dq && r != (n & 3)){ sa[ta][r] = -1e30f; sb[ta+1][r] = -1e30f; }   \
    }                                                                          \
    unsigned wA[4][2], wB[4][2];                                               \
    {                                                                          \
      const f32x2 m2 = {-M_SHIFT, -M_SHIFT};                                   \
      _Pragma("unroll")                                                        \
      for (int t = 0; t < 4; t++){                                             \
        f32x2 y0 = (f32x2){sa[t][0], sa[t][1]} * C_SCALE + m2;                 \
        f32x2 y1 = (f32x2){sa[t][2], sa[t][3]} * C_SCALE + m2;                 \
        float p0 = EXP2F(y0.x), p1 = EXP2F(y0.y);                              \
        float p2 = EXP2F(y1.x), p3 = EXP2F(y1.y);                              \
        la2 += (f32x2){p0, p1}; la2 += (f32x2){p2, p3};                        \
        wA[t][0] = cvtpk(p0, p1); wA[t][1] = cvtpk(p2, p3);                    \
      }                                                                        \
      _Pragma("unroll")                                                        \
      for (int t = 0; t < 4; t++){                                             \
        f32x2 y0 = (f32x2){sb[t][0], sb[t][1]} * C_SCALE + m2;                 \
        f32x2 y1 = (f32x2){sb[t][2], sb[t][3]} * C_SCALE + m2;                 \
        float p0 = EXP2F(y0.x), p1 = EXP2F(y0.y);                              \
        float p2 = EXP2F(y1.x), p3 = EXP2F(y1.y);                              \
        lb2 += (f32x2){p0, p1}; lb2 += (f32x2){p2, p3};                        \
        wB[t][0] = cvtpk(p0, p1); wB[t][1] = cvtpk(p2, p3);                    \
      }                                                                        \
    }                                                                          \
    U4 apA0, apA1, apB0, apB1;                                                 \
    xpose_p(wA, apA0, apA1);                                                   \
    xpose_p(wB, apB0, apB1);                                                   \
    __builtin_amdgcn_s_setprio(1);                                             \
    o0a = __builtin_amdgcn_mfma_f32_16x16x32_bf16(apA0.v, bv00.v, o0a, 0, 0, 0); \
    o0a = __builtin_amdgcn_mfma_f32_16x16x32_bf16(apA1.v, bv01.v, o0a, 0, 0, 0); \
    o1a = __builtin_amdgcn_mfma_f32_16x16x32_bf16(apA0.v, bv10.v, o1a, 0, 0, 0); \
    o1a = __builtin_amdgcn_mfma_f32_16x16x32_bf16(apA1.v, bv11.v, o1a, 0, 0, 0); \
    o0b = __builtin_amdgcn_mfma_f32_16x16x32_bf16(apB0.v, bv00.v, o0b, 0, 0, 0); \
    o0b = __builtin_amdgcn_mfma_f32_16x16x32_bf16(apB1.v, bv01.v, o0b, 0, 0, 0); \
    o1b = __builtin_amdgcn_mfma_f32_16x16x32_bf16(apB0.v, bv10.v, o1b, 0, 0, 0); \
    o1b = __builtin_amdgcn_mfma_f32_16x16x32_bf16(apB1.v, bv11.v, o1b, 0, 0, 0); \
    __builtin_amdgcn_s_setprio(0);                                             \
  }

__global__ __launch_bounds__(512, 2) void cswin_attn_kernel(
    const float* __restrict__ qg,
    const float* __restrict__ kg,
    const float* __restrict__ vg,
    const float* __restrict__ cwg,
    float* __restrict__ outg)
{
  __shared__ __align__(16) unsigned char smem[LDS_BYTES];
  const int tid = threadIdx.x;
  const int lane = tid & 63;
  const int wave = tid >> 6;          // 0..7
  const int qd = lane >> 4;
  const int n  = lane & 15;

  const int swn = (n & 7) << 2;            // VT read swizzle (dword units)
  const int xb0 = ((4 * qd) ^ swn) << 2;   // VT: byte off of swizzled dword 4qd
  const int xb1 = xb0 ^ 64;

  // grid 512: bh = bid&255 (win-head), half = bid>>8 (row-half).
  // Both halves of a win-head share bid%8-slot -> same XCD L2.
  const int bid  = blockIdx.x;
  const int bh   = bid & 255;
  const int half = bid >> 8;
  const int head = bh & 3;
  const int bw = bh >> 2;
  const int b  = bw >> 5;
  const int jj = bw & 31;

  // token l: offset = wbase + (l>>3)*32768 + ((l>>2)&1)*512 + (l&3)*128
  const size_t wbase = (size_t)b * 2097152 + (size_t)(jj * 2) * 512 + head * 32;
  const size_t lane_base = wbase + (size_t)(n >> 3) * 32768 + (size_t)((n >> 2) & 1) * 512 +
                           (size_t)(n & 3) * 128 + qd * 8;

  const int row0  = half * 256 + wave * 32;   // this wave's 2 m-tiles
  const int tilea = row0 >> 4;          // even; m-tile B = tilea+1
  const int cka   = tilea >> 2;         // chunk holding both diag tiles
  const int ta    = tilea & 3;          // in-chunk tile idx of A's diag

  // ---- issue Q loads first (latency hidden under staging) ----
  float4 qra0, qra1, qrb0, qrb1;
  {
    const float* qa = qg + lane_base + (size_t)tilea * 65536;
    const float* qb = qa + 65536;
    qra0 = ((const float4*)qa)[0]; qra1 = ((const float4*)qa)[1];
    qrb0 = ((const float4*)qb)[0]; qrb1 = ((const float4*)qb)[1];
  }

  // ---- stage V -> VT and K -> KS (full win-head per block), coalesced ----
  // slice (T, p): T = tk + j*64, tk = tid>>3 (64 tokens/round), p = tid&7
  // (8 lanes = one token's contiguous 128B). 2 rounds x 4 tokens each.
  {
    const int tk = tid >> 3;
    const int p  = tid & 7;
    const int R0 = 4 * p;
#pragma unroll 1
    for (int rr = 0; rr < 2; rr++){
      const int T0 = tk + (rr * 4 + 0) * 64;
      const int T1 = tk + (rr * 4 + 1) * 64;
      const int T2 = tk + (rr * 4 + 2) * 64;
      const int T3 = tk + (rr * 4 + 3) * 64;
      float4 va0, va1, va2, va3, ka0, ka1, ka2, ka3;
      {
        size_t o0 = wbase + (size_t)(T0 >> 3) * 32768 + (size_t)((T0 >> 2) & 1) * 512 + (size_t)(T0 & 3) * 128 + p * 4;
        size_t o1 = wbase + (size_t)(T1 >> 3) * 32768 + (size_t)((T1 >> 2) & 1) * 512 + (size_t)(T1 & 3) * 128 + p * 4;
        size_t o2 = wbase + (size_t)(T2 >> 3) * 32768 + (size_t)((T2 >> 2) & 1) * 512 + (size_t)(T2 & 3) * 128 + p * 4;
        size_t o3 = wbase + (size_t)(T3 >> 3) * 32768 + (size_t)((T3 >> 2) & 1) * 512 + (size_t)(T3 & 3) * 128 + p * 4;
        va0 = *(const float4*)(vg + o0); ka0 = *(const float4*)(kg + o0);
        va1 = *(const float4*)(vg + o1); ka1 = *(const float4*)(kg + o1);
        va2 = *(const float4*)(vg + o2); ka2 = *(const float4*)(kg + o2);
        va3 = *(const float4*)(vg + o3); ka3 = *(const float4*)(kg + o3);
      }
#define STAGE_WR(VA, KA, TT)                                                         \
      {                                                                              \
        const int T_ = (TT);                                                         \
        unsigned short h0 = (unsigned short)cvtpk((VA).x, (VA).x);                   \
        unsigned short h1 = (unsigned short)cvtpk((VA).y, (VA).y);                   \
        unsigned short h2 = (unsigned short)cvtpk((VA).z, (VA).z);                   \
        unsigned short h3 = (unsigned short)cvtpk((VA).w, (VA).w);                   \
        *(unsigned short*)(smem + VT_OFF + (R0+0) * 1024 + ((T_*2) ^ (((R0+0)&7)<<4))) = h0; \
        *(unsigned short*)(smem + VT_OFF + (R0+1) * 1024 + ((T_*2) ^ (((R0+1)&7)<<4))) = h1; \
        *(unsigned short*)(smem + VT_OFF + (R0+2) * 1024 + ((T_*2) ^ (((R0+2)&7)<<4))) = h2; \
        *(unsigned short*)(smem + VT_OFF + (R0+3) * 1024 + ((T_*2) ^ (((R0+3)&7)<<4))) = h3; \
        uint2 kw; kw.x = cvtpk((KA).x, (KA).y); kw.y = cvtpk((KA).z, (KA).w);        \
        *(uint2*)(smem + KS_OFF + T_ * 64 + ((p*8) ^ (((T_>>1)&3)<<4))) = kw;        \
      }
      STAGE_WR(va0, ka0, T0)
      STAGE_WR(va1, ka1, T1)
      STAGE_WR(va2, ka2, T2)
      STAGE_WR(va3, ka3, T3)
#undef STAGE_WR
    }
  }

  // Q pack overlaps the staging drain (before the barrier)
  U4 bqa = pack8(qra0, qra1);
  U4 bqb = pack8(qrb0, qrb1);

  __syncthreads();

  f32x4 o0a={0,0,0,0}, o1a={0,0,0,0}, o0b={0,0,0,0}, o1b={0,0,0,0};
  f32x2 la2 = {0.f,0.f}, lb2 = {0.f,0.f};   // packed per-lane softmax sums

  // per-lane KS read base: token n of each tile, ch qd*8..+7 (swizzled).
  // swizzle key for row T=16t+n is ((T>>1)&3) = ((n>>1)&3)  (16t ≡ 0 mod 8).
  const int kxb = (qd * 16) ^ (((n >> 1) & 3) << 4);
  const unsigned char* kbase = smem + KS_OFF + n * 64 + kxb;

  // ---- prologue: K fragments for chunk 0 ----
  U4 aka0, aka1, aka2, aka3, akb0, akb1, akb2, akb3;
  aka0.u = *(const uint4*)(kbase);
  aka1.u = *(const uint4*)(kbase + 1024);
  aka2.u = *(const uint4*)(kbase + 2048);
  aka3.u = *(const uint4*)(kbase + 3072);

#pragma unroll 1
  for (int cc = 0; cc < 4; cc++){
    CHUNK(cc * 2,     aka0, aka1, aka2, aka3, akb0, akb1, akb2, akb3)
    CHUNK(cc * 2 + 1, akb0, akb1, akb2, akb3, aka0, aka1, aka2, aka3)
  }

  // ---- conv weights (global loads overlap the reductions below) ----
  float w9[2][9];
#pragma unroll
  for (int nt = 0; nt < 2; nt++){
    int c = head * 32 + nt * 16 + n;
#pragma unroll
    for (int t9 = 0; t9 < 9; t9++) w9[nt][t9] = cwg[c * 9 + t9];
  }

  // ---- final cross-lane l reduction (once, not per chunk) ----
  float la = la2.x + la2.y, lb = lb2.x + lb2.y;
  la += __shfl_xor(la, 16); la += __shfl_xor(la, 32);
  lb += __shfl_xor(lb, 16); lb += __shfl_xor(lb, 32);

  const float ila = 1.f / la, ilb = 1.f / lb;

  // ---- epilogue: compute both nt halves first, then store adjacently ----
#pragma unroll
  for (int mt = 0; mt < 2; mt++){
    const int m0 = row0 + mt * 16;
    const float ilv = mt ? ilb : ila;
    const f32x4 oo0 = mt ? o0b : o0a;
    const f32x4 oo1 = mt ? o1b : o1a;
    float il[4];
#pragma unroll
    for (int r = 0; r < 4; r++) il[r] = __shfl(ilv, qd * 4 + r);

    const int sp = (m0 >> 2) + qd;
    const int h_ = sp >> 1, w_ = sp & 1;

    float accs[2], cw2[2], vfs[2][4];
#pragma unroll
    for (int nt = 0; nt < 2; nt++){
      const int d = nt * 16 + n;
      const unsigned char* VTd = smem + VT_OFF + d * 1024;   // (d&7)==(n&7)
      float acc = 0.f;
#pragma unroll
      for (int dy = -1; dy <= 1; dy++){
        int h2 = h_ + dy;
        bool hv = (h2 >= 0) && (h2 <= 63);
        int h2c = hv ? h2 : h_;   // safe in-range address for masked lanes
#pragma unroll
        for (int wp = 0; wp < 2; wp++){
          bool valid = hv && !((dy == 0) && (wp == w_));
          int ti = (dy + 1) * 3 + 1 + wp - w_;
          int spn = h2c * 2 + wp;
          uint2 sv = *(const uint2*)(VTd + (((2 * spn) ^ swn) << 2));
          float s = bf2f((unsigned short)(sv.x & 0xffff)) + bf2f((unsigned short)(sv.x >> 16))
                  + bf2f((unsigned short)(sv.y & 0xffff)) + bf2f((unsigned short)(sv.y >> 16));
          acc += (valid ? w9[nt][ti] : 0.f) * s;
        }
      }
      accs[nt] = acc;
      cw2[nt] = w9[nt][4];
      uint2 vv4 = *(const uint2*)(VTd + ((((m0 >> 1) + 2 * qd) ^ swn) << 2));
      vfs[nt][0] = bf2f((unsigned short)(vv4.x & 0xffff));
      vfs[nt][1] = bf2f((unsigned short)(vv4.x >> 16));
      vfs[nt][2] = bf2f((unsigned short)(vv4.y & 0xffff));
      vfs[nt][3] = bf2f((unsigned short)(vv4.y >> 16));
    }

    const size_t obase = (size_t)b * 2097152 + (size_t)h_ * 32768 +
                         (size_t)(jj * 2 + w_) * 512 + head * 32;
#pragma unroll
    for (int r = 0; r < 4; r++){
      float r0 = oo0[r] * il[r] + accs[0] + cw2[0] * vfs[0][r];
      float r1 = oo1[r] * il[r] + accs[1] + cw2[1] * vfs[1][r];
      outg[obase + (size_t)r * 128 + n]      = r0;   // line half 1
      outg[obase + (size_t)r * 128 + 16 + n] = r1;   // line half 2 (adjacent)
    }
  }
}

extern "C" void kernel_launch(void* const* d_in, const int* in_sizes, int n_in,
                              void* d_out, int out_size, void* d_ws, size_t ws_size,
                              hipStream_t stream) {
  (void)in_sizes; (void)n_in; (void)d_ws; (void)ws_size; (void)out_size;
  cswin_attn_kernel<<<dim3(512), dim3(512), 0, stream>>>(
      (const float*)d_in[0], (const float*)d_in[1], (const float*)d_in[2],
      (const float*)d_in[3], (float*)d_out);
}